// Round 1
// baseline (117.340 us; speedup 1.0000x reference)
//
#include <hip/hip_runtime.h>
#include <hip/hip_bf16.h>

// Problem constants (B,H,W,C) = (4,56,56,256), nh=8, K=7, lr=4, hd=32
#define BD 4
#define HD_ 56
#define WD 56
#define CD 256
#define NH 8
#define KW 7
#define LR 4
#define HDIM 32
#define MB (HD_*WD)              // 3136 rows per batch
#define NROWS (BD*MB)            // 12544 total rows
#define QK_PER_B (HD_*WD*32)     // 100352  (q/k per-batch elements)
#define V_PER_B  (HD_*WD*256)    // 802816

typedef short short8 __attribute__((ext_vector_type(8)));   // 8 bf16 (4 VGPRs)
typedef float floatx4 __attribute__((ext_vector_type(4)));  // MFMA C/D

static __device__ inline ushort f2bf(float f) {
    __hip_bfloat16 h = __float2bfloat16(f);
    return *(ushort*)&h;
}
static __device__ inline float bf2f(uint h16) {          // h16 = bf16 in low 16 bits
    union { uint u; float f; } c; c.u = h16 << 16; return c.f;
}
static __device__ inline float bf2f_hi(uint u) {         // bf16 in high 16 bits
    union { uint v; float f; } c; c.v = u & 0xffff0000u; return c.f;
}

// global -> LDS async DMA, 16B per lane. LDS dest is wave-uniform base +
// lane*16 (HW behavior); global src is per-lane.
typedef const __attribute__((address_space(1))) void* gp1_t;
typedef __attribute__((address_space(3))) void* sp3_t;
static __device__ __forceinline__ void glds16(const void* g, void* s) {
    __builtin_amdgcn_global_load_lds((gp1_t)g, (sp3_t)s, 16, 0, 0);
}

// ---------------- prep: x->bf16 + transposed bf16 weights + packed bias -----
// idx ranges: [0,401408) xb 8-wide; then WpkT 81920; WpT 65536; pb 320.
__global__ __launch_bounds__(256) void prep_all(
    const float* __restrict__ x,
    const float* __restrict__ Wq, const float* __restrict__ Wk,
    const float* __restrict__ Wv, const float* __restrict__ bq,
    const float* __restrict__ bk, const float* __restrict__ bv,
    const float* __restrict__ Wp,
    ushort* __restrict__ xb, ushort* __restrict__ WpkT,
    ushort* __restrict__ WpT, float* __restrict__ pb)
{
    int idx = blockIdx.x * 256 + threadIdx.x;
    if (idx < 401408) {
        float4 f0 = *(const float4*)&x[idx * 8];
        float4 f1 = *(const float4*)&x[idx * 8 + 4];
        union { ushort h[8]; uint4 u; } p;
        p.h[0] = f2bf(f0.x); p.h[1] = f2bf(f0.y); p.h[2] = f2bf(f0.z); p.h[3] = f2bf(f0.w);
        p.h[4] = f2bf(f1.x); p.h[5] = f2bf(f1.y); p.h[6] = f2bf(f1.z); p.h[7] = f2bf(f1.w);
        *(uint4*)&xb[idx * 8] = p.u;
    } else if (idx < 401408 + 81920) {
        int j = idx - 401408;
        int n = j >> 8, k = j & 255;
        float v;
        if (n < 32)       v = Wq[k * 32 + n];
        else if (n < 64)  v = Wk[k * 32 + (n - 32)];
        else              v = Wv[k * 256 + (n - 64)];
        WpkT[j] = f2bf(v);
    } else if (idx < 401408 + 81920 + 65536) {
        int j = idx - (401408 + 81920);
        int n = j >> 8, k = j & 255;
        WpT[j] = f2bf(Wp[k * 256 + n]);
    } else if (idx < 401408 + 81920 + 65536 + 320) {
        int n = idx - (401408 + 81920 + 65536);
        pb[n] = (n < 32) ? bq[n] : (n < 64) ? bk[n - 32] : bv[n - 64];
    }
}

// ---------------- shared GEMM core: 128x64 tile, BK=64, global_load_lds -----
// A [M][256] bf16, B(T) [N][256] bf16. 256 thr = 4 waves (2x2 wave grid),
// each wave computes 64x32 = acc[4][2] of 16x16 frags. Linear LDS
// A[128][64] / B[64][64] with rule-#21 both-sides XOR swizzle:
//   lds_byte(row,kb) = row*128 + (kb ^ ((row&7)<<4))
// staged via inverse-swizzled global source, read with the same XOR ->
// conflict-free ds_read_b128 (lanes cover all 32 banks).
static __device__ __forceinline__ void gemm_core_128x64(
    const ushort* __restrict__ Ag, const ushort* __restrict__ Bg,
    ushort* As, ushort* Bs, int m0, int n0, int t, floatx4 (&acc)[4][2])
{
    const int lane = t & 63, w = t >> 6;
    const int lx = lane & 7, ly = lane >> 3;     // staging: 8 rows x 8 chunks
    const int koff = (lx ^ ly) << 3;             // ushort offset in 64-wide row
    const int col = lane & 15, quad = lane >> 4;
    const int swz = (col & 7) << 4;              // read-side byte XOR
    const int wm = w >> 1, wn = w & 1;
    char* Ac = (char*)As;
    char* Bc = (char*)Bs;

    for (int k0 = 0; k0 < 256; k0 += 64) {
        __syncthreads();                          // prev compute done
        // A: 16 KB = 16 chunks of 1 KB; wave w stages chunks 4w..4w+3
#pragma unroll
        for (int l = 0; l < 4; ++l) {
            int c = (w << 2) + l;
            int row = (c << 3) + ly;
            glds16(&Ag[(m0 + row) * 256 + k0 + koff], &As[c << 9]);
        }
        // B: 8 KB = 8 chunks; wave w stages chunks 2w..2w+1
#pragma unroll
        for (int l = 0; l < 2; ++l) {
            int c = (w << 1) + l;
            int row = (c << 3) + ly;
            glds16(&Bg[(n0 + row) * 256 + k0 + koff], &Bs[c << 9]);
        }
        __syncthreads();                          // barrier drains vmcnt(0)
#pragma unroll
        for (int kk = 0; kk < 2; ++kk) {
            const int kx = ((kk << 6) + (quad << 4)) ^ swz;
            short8 b0 = *(short8*)(Bc + ((wn << 5) + col) * 128 + kx);
            short8 b1 = *(short8*)(Bc + ((wn << 5) + 16 + col) * 128 + kx);
#pragma unroll
            for (int mt = 0; mt < 4; ++mt) {
                short8 a = *(short8*)(Ac + ((wm << 6) + (mt << 4) + col) * 128 + kx);
                acc[mt][0] = __builtin_amdgcn_mfma_f32_16x16x32_bf16(a, b0, acc[mt][0], 0, 0, 0);
                acc[mt][1] = __builtin_amdgcn_mfma_f32_16x16x32_bf16(a, b1, acc[mt][1], 0, 0, 0);
            }
        }
    }
}

// ---------------- MFMA GEMM: QKV projection -------------------------------
// grid (5, 98): n0 = 0 block covers Q(0..31)+K(32..63); others V.
__global__ __launch_bounds__(256) void mfma_qkv(
    const ushort* __restrict__ xb, const ushort* __restrict__ Bt,
    const float* __restrict__ pb, ushort* __restrict__ Qb,
    ushort* __restrict__ Kb, ushort* __restrict__ Vb)
{
    __shared__ ushort As[128 * 64];   // 16 KB
    __shared__ ushort Bs[64 * 64];    // 8 KB
    const int t = threadIdx.x;
    const int m0 = blockIdx.y * 128, n0 = blockIdx.x * 64;

    floatx4 acc[4][2] = {};
    gemm_core_128x64(xb, Bt, As, Bs, m0, n0, t, acc);

    const int lane = t & 63, w = t >> 6;
    const int col = lane & 15, quad = lane >> 4;
    const int wm = w >> 1, wn = w & 1;
#pragma unroll
    for (int mt = 0; mt < 4; ++mt) {
#pragma unroll
        for (int nt = 0; nt < 2; ++nt) {
            int gn = n0 + (wn << 5) + (nt << 4) + col;
            float bias = pb[gn];
#pragma unroll
            for (int rg = 0; rg < 4; ++rg) {
                int m = m0 + (wm << 6) + (mt << 4) + (quad << 2) + rg;
                ushort h = f2bf(acc[mt][nt][rg] + bias);
                if (gn < 32)        Qb[m * 32 + gn] = h;
                else if (gn < 64)   Kb[m * 32 + (gn - 32)] = h;
                else                Vb[m * 256 + (gn - 64)] = h;
            }
        }
    }
}

// ---------------- MFMA GEMM: output projection ----------------------------
__global__ __launch_bounds__(256) void mfma_out(
    const ushort* __restrict__ Ag, const ushort* __restrict__ Bt,
    const float* __restrict__ bp, float* __restrict__ out)
{
    __shared__ ushort As[128 * 64];
    __shared__ ushort Bs[64 * 64];
    const int t = threadIdx.x;
    const int m0 = blockIdx.y * 128, n0 = blockIdx.x * 64;

    floatx4 acc[4][2] = {};
    gemm_core_128x64(Ag, Bt, As, Bs, m0, n0, t, acc);

    const int lane = t & 63, w = t >> 6;
    const int col = lane & 15, quad = lane >> 4;
    const int wm = w >> 1, wn = w & 1;
#pragma unroll
    for (int mt = 0; mt < 4; ++mt) {
#pragma unroll
        for (int nt = 0; nt < 2; ++nt) {
            int gn = n0 + (wn << 5) + (nt << 4) + col;
            float bias = bp[gn];
#pragma unroll
            for (int rg = 0; rg < 4; ++rg) {
                int m = m0 + (wm << 6) + (mt << 4) + (quad << 2) + rg;
                out[m * 256 + gn] = acc[mt][nt][rg] + bias;
            }
        }
    }
}

// ---------------- NATTEN attention: fp32 K/V in LDS, single-pass softmax ----
// bf16 unpack done ONCE at staging (each V pos reused ~16x). V slabs [d4][197]
// float4: 197 stride => p-lanes land on distinct 4-bank groups, pos-sharing
// lanes 2-way (free). grid (7,7,32), block 256 = 4 lanes/query.
// launch_bounds min-waves/EU = 5: LDS (29 KB) caps residency at 5 blocks/CU,
// so 8 was over-constraining the register allocator for unreachable occupancy.
__global__ __launch_bounds__(256, 5) void natten_attn_t(
    const ushort* __restrict__ Qb, const ushort* __restrict__ Kb,
    const ushort* __restrict__ Vb, const float* __restrict__ rpb,
    ushort* __restrict__ Ab)
{
    __shared__ float4 Ksf[196];       // 14x14 k-window fp32 (3.1 KB)
    __shared__ float4 Vsf[8 * 197];   // [d4][pos] fp32, padded slabs (25.2 KB)
    __shared__ float  Rs[169];

    const int tj = blockIdx.x, ti = blockIdx.y;
    const int n = blockIdx.z & 7, b = blockIdx.z >> 3;
    const int t = threadIdx.x;
    const int i0 = ti * 8, j0 = tj * 8;
    const int rs = min(max(i0 - 3, 0), HD_ - 14);
    const int cs = min(max(j0 - 3, 0), WD - 14);

    // raw-reshape views:
    const ushort* kb = Kb + b * QK_PER_B + n * (HD_ * WD * LR);
    const ushort* vb = Vb + b * V_PER_B + n * (HD_ * WD * HDIM);

    if (t < 196) {
        int r = t / 14, c = t % 14;
        union { uint2 u; uint w[2]; } kr;
        kr.u = *(const uint2*)&kb[(rs + r) * (WD * LR) + (cs + c) * LR];
        Ksf[t] = make_float4(bf2f(kr.w[0] & 0xffff), bf2f_hi(kr.w[0]),
                             bf2f(kr.w[1] & 0xffff), bf2f_hi(kr.w[1]));
    }
    if (t < 169) Rs[t] = rpb[n * 169 + t];
    for (int idx = t; idx < 784; idx += 256) {      // 196 pos x 4 octs (8ch each)
        int oct = idx & 3, pos = idx >> 2;
        int r = pos / 14, c = pos % 14;
        union { uint4 u; uint w[4]; } vr;
        vr.u = *(const uint4*)&vb[(rs + r) * (WD * HDIM) + (cs + c) * HDIM + oct * 8];
        Vsf[(2 * oct) * 197 + pos] =
            make_float4(bf2f(vr.w[0] & 0xffff), bf2f_hi(vr.w[0]),
                        bf2f(vr.w[1] & 0xffff), bf2f_hi(vr.w[1]));
        Vsf[(2 * oct + 1) * 197 + pos] =
            make_float4(bf2f(vr.w[2] & 0xffff), bf2f_hi(vr.w[2]),
                        bf2f(vr.w[3] & 0xffff), bf2f_hi(vr.w[3]));
    }
    __syncthreads();

    const int q  = t >> 2, p = t & 3;
    const int qi = q >> 3, qj = q & 7;
    const int i = i0 + qi, j = j0 + qj;
    const int sh = min(max(i - 3, 0), HD_ - KW);
    const int sw = min(max(j - 3, 0), WD - KW);
    const int oh = sh - rs, ow = sw - cs;

    union { uint2 u; uint w[2]; } qr;
    qr.u = *(const uint2*)&Qb[b * QK_PER_B + n * (HD_ * WD * LR) + i * (WD * LR) + j * LR];
    const float scale = 0.17677669529663687f;
    float qx = bf2f(qr.w[0] & 0xffff) * scale, qy = bf2f_hi(qr.w[0]) * scale;
    float qz = bf2f(qr.w[1] & 0xffff) * scale, qw = bf2f_hi(qr.w[1]) * scale;

    const int rb0 = (sh - i + 6) * 13 + (sw - j + 6);

    float sum = 0.f;
    float a[8] = {0.f, 0.f, 0.f, 0.f, 0.f, 0.f, 0.f, 0.f};
    const float4* v0 = &Vsf[(2 * p) * 197];
    const float4* v1 = &Vsf[(2 * p + 1) * 197];
    for (int kh = 0; kh < KW; ++kh) {
        int kpos  = (oh + kh) * 14 + ow;
        int rbase = rb0 + kh * 13;
#pragma unroll
        for (int kw = 0; kw < KW; ++kw) {
            float4 kf = Ksf[kpos + kw];
            float d = Rs[rbase + kw];
            d = fmaf(qx, kf.x, d);
            d = fmaf(qy, kf.y, d);
            d = fmaf(qz, kf.z, d);
            d = fmaf(qw, kf.w, d);
            float e = __expf(d);
            sum += e;
            float4 x0 = v0[kpos + kw];
            float4 x1 = v1[kpos + kw];
            a[0] = fmaf(e, x0.x, a[0]); a[1] = fmaf(e, x0.y, a[1]);
            a[2] = fmaf(e, x0.z, a[2]); a[3] = fmaf(e, x0.w, a[3]);
            a[4] = fmaf(e, x1.x, a[4]); a[5] = fmaf(e, x1.y, a[5]);
            a[6] = fmaf(e, x1.z, a[6]); a[7] = fmaf(e, x1.w, a[7]);
        }
    }
    float inv = 1.0f / sum;

    // bf16 store: 8 channels = 16B at channel block n*32 + p*8
    union { ushort h[8]; uint4 u; } pk;
#pragma unroll
    for (int c = 0; c < 8; ++c) pk.h[c] = f2bf(a[c] * inv);
    *(uint4*)&Ab[(((b * HD_ + i) * WD + j)) * CD + n * HDIM + p * 8] = pk.u;
}

extern "C" void kernel_launch(void* const* d_in, const int* in_sizes, int n_in,
                              void* d_out, int out_size, void* d_ws, size_t ws_size,
                              hipStream_t stream) {
    const float* x   = (const float*)d_in[0];
    const float* Wq  = (const float*)d_in[1];
    const float* bq  = (const float*)d_in[2];
    const float* Wk  = (const float*)d_in[3];
    const float* bk  = (const float*)d_in[4];
    const float* Wv  = (const float*)d_in[5];
    const float* bv  = (const float*)d_in[6];
    const float* rpb = (const float*)d_in[7];
    const float* Wp  = (const float*)d_in[8];
    const float* bp  = (const float*)d_in[9];
    float* out = (float*)d_out;

    // workspace layout — bf16 intermediates; ~21 MB of 256 MiB ws
    ushort* WpkT = (ushort*)d_ws;          // 81920
    ushort* WpT  = WpkT + 81920;           // 65536
    ushort* Ab   = WpT + 65536;            // 3211264
    ushort* Qb   = Ab + 3211264;           // 401408
    ushort* Kb   = Qb + BD * QK_PER_B;     // 401408
    ushort* Vb   = Kb + BD * QK_PER_B;     // 3211264
    ushort* xb   = Vb + BD * V_PER_B;      // 3211264 (x as bf16, [12544][256])
    float*  pb   = (float*)(xb + 3211264); // 320

    // 401408 (xb, 8-wide) + 81920 + 65536 + 320 = 549184 work items
    prep_all<<<(549184 + 255) / 256, 256, 0, stream>>>(
        x, Wq, Wk, Wv, bq, bk, bv, Wp, xb, WpkT, WpT, pb);

    mfma_qkv<<<dim3(5, NROWS / 128), 256, 0, stream>>>(xb, WpkT, pb, Qb, Kb, Vb);

    natten_attn_t<<<dim3(7, 7, 32), 256, 0, stream>>>(Qb, Kb, Vb, rpb, Ab);

    mfma_out<<<dim3(4, NROWS / 128), 256, 0, stream>>>(Ab, WpT, bp, out);
}

// Round 2
// 114.553 us; speedup vs baseline: 1.0243x; 1.0243x over previous
//
#include <hip/hip_runtime.h>
#include <hip/hip_bf16.h>

// Problem constants (B,H,W,C) = (4,56,56,256), nh=8, K=7, lr=4, hd=32
#define BD 4
#define HD_ 56
#define WD 56
#define CD 256
#define NH 8
#define KW 7
#define LR 4
#define HDIM 32
#define MB (HD_*WD)              // 3136 rows per batch
#define NROWS (BD*MB)            // 12544 total rows
#define QK_PER_B (HD_*WD*32)     // 100352  (q/k per-batch elements)
#define V_PER_B  (HD_*WD*256)    // 802816

typedef short short8 __attribute__((ext_vector_type(8)));   // 8 bf16 (4 VGPRs)
typedef float floatx4 __attribute__((ext_vector_type(4)));  // MFMA C/D

static __device__ inline ushort f2bf(float f) {
    __hip_bfloat16 h = __float2bfloat16(f);
    return *(ushort*)&h;
}
static __device__ inline float bf2f(uint h16) {          // h16 = bf16 in low 16 bits
    union { uint u; float f; } c; c.u = h16 << 16; return c.f;
}
static __device__ inline float bf2f_hi(uint u) {         // bf16 in high 16 bits
    union { uint v; float f; } c; c.v = u & 0xffff0000u; return c.f;
}

// global -> LDS async DMA, 16B per lane. LDS dest is wave-uniform base +
// lane*16 (HW behavior); global src is per-lane.
typedef const __attribute__((address_space(1))) void* gp1_t;
typedef __attribute__((address_space(3))) void* sp3_t;
static __device__ __forceinline__ void glds16(const void* g, void* s) {
    __builtin_amdgcn_global_load_lds((gp1_t)g, (sp3_t)s, 16, 0, 0);
}

// ---------------- prep: x->bf16 + transposed bf16 weights + packed bias -----
// idx ranges: [0,401408) xb 8-wide; then WpkT 81920; WpT 65536; pb 320.
__global__ __launch_bounds__(256) void prep_all(
    const float* __restrict__ x,
    const float* __restrict__ Wq, const float* __restrict__ Wk,
    const float* __restrict__ Wv, const float* __restrict__ bq,
    const float* __restrict__ bk, const float* __restrict__ bv,
    const float* __restrict__ Wp,
    ushort* __restrict__ xb, ushort* __restrict__ WpkT,
    ushort* __restrict__ WpT, float* __restrict__ pb)
{
    int idx = blockIdx.x * 256 + threadIdx.x;
    if (idx < 401408) {
        float4 f0 = *(const float4*)&x[idx * 8];
        float4 f1 = *(const float4*)&x[idx * 8 + 4];
        union { ushort h[8]; uint4 u; } p;
        p.h[0] = f2bf(f0.x); p.h[1] = f2bf(f0.y); p.h[2] = f2bf(f0.z); p.h[3] = f2bf(f0.w);
        p.h[4] = f2bf(f1.x); p.h[5] = f2bf(f1.y); p.h[6] = f2bf(f1.z); p.h[7] = f2bf(f1.w);
        *(uint4*)&xb[idx * 8] = p.u;
    } else if (idx < 401408 + 81920) {
        int j = idx - 401408;
        int n = j >> 8, k = j & 255;
        float v;
        if (n < 32)       v = Wq[k * 32 + n];
        else if (n < 64)  v = Wk[k * 32 + (n - 32)];
        else              v = Wv[k * 256 + (n - 64)];
        WpkT[j] = f2bf(v);
    } else if (idx < 401408 + 81920 + 65536) {
        int j = idx - (401408 + 81920);
        int n = j >> 8, k = j & 255;
        WpT[j] = f2bf(Wp[k * 256 + n]);
    } else if (idx < 401408 + 81920 + 65536 + 320) {
        int n = idx - (401408 + 81920 + 65536);
        pb[n] = (n < 32) ? bq[n] : (n < 64) ? bk[n - 32] : bv[n - 64];
    }
}

// ---------------- shared GEMM core: 128x64 tile, BK=64, global_load_lds -----
static __device__ __forceinline__ void gemm_core_128x64(
    const ushort* __restrict__ Ag, const ushort* __restrict__ Bg,
    ushort* As, ushort* Bs, int m0, int n0, int t, floatx4 (&acc)[4][2])
{
    const int lane = t & 63, w = t >> 6;
    const int lx = lane & 7, ly = lane >> 3;     // staging: 8 rows x 8 chunks
    const int koff = (lx ^ ly) << 3;             // ushort offset in 64-wide row
    const int col = lane & 15, quad = lane >> 4;
    const int swz = (col & 7) << 4;              // read-side byte XOR
    const int wm = w >> 1, wn = w & 1;
    char* Ac = (char*)As;
    char* Bc = (char*)Bs;

    for (int k0 = 0; k0 < 256; k0 += 64) {
        __syncthreads();                          // prev compute done
#pragma unroll
        for (int l = 0; l < 4; ++l) {
            int c = (w << 2) + l;
            int row = (c << 3) + ly;
            glds16(&Ag[(m0 + row) * 256 + k0 + koff], &As[c << 9]);
        }
#pragma unroll
        for (int l = 0; l < 2; ++l) {
            int c = (w << 1) + l;
            int row = (c << 3) + ly;
            glds16(&Bg[(n0 + row) * 256 + k0 + koff], &Bs[c << 9]);
        }
        __syncthreads();                          // barrier drains vmcnt(0)
#pragma unroll
        for (int kk = 0; kk < 2; ++kk) {
            const int kx = ((kk << 6) + (quad << 4)) ^ swz;
            short8 b0 = *(short8*)(Bc + ((wn << 5) + col) * 128 + kx);
            short8 b1 = *(short8*)(Bc + ((wn << 5) + 16 + col) * 128 + kx);
#pragma unroll
            for (int mt = 0; mt < 4; ++mt) {
                short8 a = *(short8*)(Ac + ((wm << 6) + (mt << 4) + col) * 128 + kx);
                acc[mt][0] = __builtin_amdgcn_mfma_f32_16x16x32_bf16(a, b0, acc[mt][0], 0, 0, 0);
                acc[mt][1] = __builtin_amdgcn_mfma_f32_16x16x32_bf16(a, b1, acc[mt][1], 0, 0, 0);
            }
        }
    }
}

// ---------------- MFMA GEMM: QKV projection -------------------------------
__global__ __launch_bounds__(256) void mfma_qkv(
    const ushort* __restrict__ xb, const ushort* __restrict__ Bt,
    const float* __restrict__ pb, ushort* __restrict__ Qb,
    ushort* __restrict__ Kb, ushort* __restrict__ Vb)
{
    __shared__ ushort As[128 * 64];   // 16 KB
    __shared__ ushort Bs[64 * 64];    // 8 KB
    const int t = threadIdx.x;
    const int m0 = blockIdx.y * 128, n0 = blockIdx.x * 64;

    floatx4 acc[4][2] = {};
    gemm_core_128x64(xb, Bt, As, Bs, m0, n0, t, acc);

    const int lane = t & 63, w = t >> 6;
    const int col = lane & 15, quad = lane >> 4;
    const int wm = w >> 1, wn = w & 1;
#pragma unroll
    for (int mt = 0; mt < 4; ++mt) {
#pragma unroll
        for (int nt = 0; nt < 2; ++nt) {
            int gn = n0 + (wn << 5) + (nt << 4) + col;
            float bias = pb[gn];
#pragma unroll
            for (int rg = 0; rg < 4; ++rg) {
                int m = m0 + (wm << 6) + (mt << 4) + (quad << 2) + rg;
                ushort h = f2bf(acc[mt][nt][rg] + bias);
                if (gn < 32)        Qb[m * 32 + gn] = h;
                else if (gn < 64)   Kb[m * 32 + (gn - 32)] = h;
                else                Vb[m * 256 + (gn - 64)] = h;
            }
        }
    }
}

// ---------------- MFMA GEMM: output projection ----------------------------
__global__ __launch_bounds__(256) void mfma_out(
    const ushort* __restrict__ Ag, const ushort* __restrict__ Bt,
    const float* __restrict__ bp, float* __restrict__ out)
{
    __shared__ ushort As[128 * 64];
    __shared__ ushort Bs[64 * 64];
    const int t = threadIdx.x;
    const int m0 = blockIdx.y * 128, n0 = blockIdx.x * 64;

    floatx4 acc[4][2] = {};
    gemm_core_128x64(Ag, Bt, As, Bs, m0, n0, t, acc);

    const int lane = t & 63, w = t >> 6;
    const int col = lane & 15, quad = lane >> 4;
    const int wm = w >> 1, wn = w & 1;
#pragma unroll
    for (int mt = 0; mt < 4; ++mt) {
#pragma unroll
        for (int nt = 0; nt < 2; ++nt) {
            int gn = n0 + (wn << 5) + (nt << 4) + col;
            float bias = bp[gn];
#pragma unroll
            for (int rg = 0; rg < 4; ++rg) {
                int m = m0 + (wm << 6) + (mt << 4) + (quad << 2) + rg;
                out[m * 256 + gn] = acc[mt][nt][rg] + bias;
            }
        }
    }
}

// ---------------- NATTEN attention: MFMA-PV restructure ---------------------
// Per block: 8x8 query tile, one (b, head). The 49-key windows of the 64
// queries all lie inside a shared 14x14 = 196-position support, so
// PV aggregation = dense GEMM  O[64q][32ch] = P[64][224] @ V[224][32]
// with P zero outside each query's window (zeros staged explicitly; Vt
// K-range padded with zeros -> no NaN from junk).
//  - scores computed ONCE per (q,key): the 4 p-lanes split the 7 kh rows
//    (vs 4x replication before); e written to P (bf16), per-query sum via
//    2 quad shfl_xor; normalization deferred to epilogue via invS[64].
//  - V staged bf16 (no fp32 unpack), transposed to Vt[32ch][232] via b16
//    scatter; stride 232 elems = 464B = 116 dw === 20 (mod 32) -> frag
//    ds_read_b128 start-banks uniform (conflict-free at the 8-cyc minimum).
//  - MFMA phase: wave w owns queries w*16..+15: 7 K-steps x 2 n-tiles of
//    16x16x32 bf16, fragment addressing identical to gemm_core's pattern.
// LDS 48.6 KB -> 3 blocks/CU.
__global__ __launch_bounds__(256, 3) void natten_attn_m(
    const ushort* __restrict__ Qb, const ushort* __restrict__ Kb,
    const ushort* __restrict__ Vb, const float* __restrict__ rpb,
    ushort* __restrict__ Ab)
{
    __shared__ ushort Pl[64 * 232];   // 29696 B  P[q][key] bf16 (224 used)
    __shared__ ushort Vt[32 * 232];   // 14848 B  V^T[ch][key] bf16
    __shared__ float4 Ksf[196];       // 3136 B   14x14 K window fp32
    __shared__ float  Rs[169];        // 676 B    rpb slice
    __shared__ float  invS[64];       // 256 B    1/sum per query

    const int tj = blockIdx.x, ti = blockIdx.y;
    const int n = blockIdx.z & 7, b = blockIdx.z >> 3;
    const int t = threadIdx.x;
    const int i0 = ti * 8, j0 = tj * 8;
    const int rs = min(max(i0 - 3, 0), HD_ - 14);
    const int cs = min(max(j0 - 3, 0), WD - 14);

    const ushort* kb = Kb + b * QK_PER_B + n * (HD_ * WD * LR);
    const ushort* vb = Vb + b * V_PER_B + n * (HD_ * WD * HDIM);

    // ---- phase 0: issue global prefetches (latency hidden under zero-fill)
    uint4 vreg[4];
#pragma unroll
    for (int it = 0; it < 4; ++it) {
        int idx = t + it * 256;
        if (idx < 784) {
            int pos = idx >> 2, oct = idx & 3;
            int r = pos / 14, c = pos % 14;
            vreg[it] = *(const uint4*)&vb[(rs + r) * (WD * HDIM) + (cs + c) * HDIM + oct * 8];
        }
    }
    uint2 kreg = make_uint2(0u, 0u);
    if (t < 196) {
        int r = t / 14, c = t % 14;
        kreg = *(const uint2*)&kb[(rs + r) * (WD * LR) + (cs + c) * LR];
    }
    float rreg = (t < 169) ? rpb[n * 169 + t] : 0.f;

    const int q  = t >> 2, p = t & 3;           // 4 lanes per query
    const int qi = q >> 3, qj = q & 7;
    const int i = i0 + qi, j = j0 + qj;
    uint2 qr2 = *(const uint2*)&Qb[b * QK_PER_B + n * (HD_ * WD * LR) + i * (WD * LR) + j * LR];

    // ---- zero P and Vt (NaN-safety for window holes + K-pad region)
#pragma unroll
    for (int it = 0; it < 8; ++it) {
        int idx = t + (it << 8);
        if (idx < 1856) *(uint4*)&Pl[idx << 3] = make_uint4(0, 0, 0, 0);
    }
#pragma unroll
    for (int it = 0; it < 4; ++it) {
        int idx = t + (it << 8);
        if (idx < 928) *(uint4*)&Vt[idx << 3] = make_uint4(0, 0, 0, 0);
    }
    __syncthreads();

    // ---- stage: Ksf fp32, Rs, V^T scatter (bf16)
    if (t < 196) {
        Ksf[t] = make_float4(bf2f(kreg.x & 0xffff), bf2f_hi(kreg.x),
                             bf2f(kreg.y & 0xffff), bf2f_hi(kreg.y));
    }
    if (t < 169) Rs[t] = rreg;
#pragma unroll
    for (int it = 0; it < 4; ++it) {
        int idx = t + it * 256;
        if (idx < 784) {
            int pos = idx >> 2, oct = idx & 3;
            ushort* cp = &Vt[(oct * 8) * 232 + pos];
            union { uint4 u; ushort h[8]; } vv; vv.u = vreg[it];
#pragma unroll
            for (int e = 0; e < 8; ++e) cp[e * 232] = vv.h[e];
        }
    }
    __syncthreads();

    // ---- scores: lane p handles kh rows {p, p+4}
    const int sh = min(max(i - 3, 0), HD_ - KW);
    const int sw = min(max(j - 3, 0), WD - KW);
    const int oh = sh - rs, ow = sw - cs;
    const float scale = 0.17677669529663687f;
    float qx = bf2f(qr2.x & 0xffff) * scale, qy = bf2f_hi(qr2.x) * scale;
    float qz = bf2f(qr2.y & 0xffff) * scale, qw = bf2f_hi(qr2.y) * scale;
    const int rb0 = (sh - i + 6) * 13 + (sw - j + 6);

    float sum = 0.f;
#pragma unroll
    for (int half = 0; half < 2; ++half) {
        int kh = p + (half << 2);
        if (kh < 7) {
            int kpos  = (oh + kh) * 14 + ow;
            int rbase = rb0 + kh * 13;
            ushort* prow = &Pl[q * 232 + kpos];
#pragma unroll
            for (int kw = 0; kw < 7; ++kw) {
                float4 kf = Ksf[kpos + kw];
                float d = Rs[rbase + kw];
                d = fmaf(qx, kf.x, d);
                d = fmaf(qy, kf.y, d);
                d = fmaf(qz, kf.z, d);
                d = fmaf(qw, kf.w, d);
                float e = __expf(d);
                sum += e;
                prow[kw] = f2bf(e);
            }
        }
    }
    sum += __shfl_xor(sum, 1);
    sum += __shfl_xor(sum, 2);
    if (p == 0) invS[q] = 1.0f / sum;
    __syncthreads();

    // ---- MFMA PV: wave w -> queries w*16..w*16+15
    const int lane = t & 63, w = t >> 6;
    const int col = lane & 15, quad = lane >> 4;
    floatx4 acc0 = {0.f, 0.f, 0.f, 0.f}, acc1 = {0.f, 0.f, 0.f, 0.f};
    const ushort* arow = &Pl[(w * 16 + col) * 232];
    const ushort* b0p  = &Vt[col * 232];
    const ushort* b1p  = &Vt[(col + 16) * 232];
#pragma unroll
    for (int s = 0; s < 7; ++s) {
        int ko = s * 32 + quad * 8;
        short8 a  = *(const short8*)(arow + ko);
        short8 f0 = *(const short8*)(b0p + ko);
        short8 f1 = *(const short8*)(b1p + ko);
        acc0 = __builtin_amdgcn_mfma_f32_16x16x32_bf16(a, f0, acc0, 0, 0, 0);
        acc1 = __builtin_amdgcn_mfma_f32_16x16x32_bf16(a, f1, acc1, 0, 0, 0);
    }

    // ---- epilogue: normalize + bf16 store (D: col=lane&15, row=quad*4+rg)
#pragma unroll
    for (int rg = 0; rg < 4; ++rg) {
        int qq = w * 16 + quad * 4 + rg;
        float iv = invS[qq];
        int ii = i0 + (qq >> 3), jj = j0 + (qq & 7);
        ushort* dst = &Ab[(((b * HD_ + ii) * WD + jj)) * CD + n * HDIM + col];
        dst[0]  = f2bf(acc0[rg] * iv);
        dst[16] = f2bf(acc1[rg] * iv);
    }
}

extern "C" void kernel_launch(void* const* d_in, const int* in_sizes, int n_in,
                              void* d_out, int out_size, void* d_ws, size_t ws_size,
                              hipStream_t stream) {
    const float* x   = (const float*)d_in[0];
    const float* Wq  = (const float*)d_in[1];
    const float* bq  = (const float*)d_in[2];
    const float* Wk  = (const float*)d_in[3];
    const float* bk  = (const float*)d_in[4];
    const float* Wv  = (const float*)d_in[5];
    const float* bv  = (const float*)d_in[6];
    const float* rpb = (const float*)d_in[7];
    const float* Wp  = (const float*)d_in[8];
    const float* bp  = (const float*)d_in[9];
    float* out = (float*)d_out;

    // workspace layout — bf16 intermediates; ~21 MB of 256 MiB ws
    ushort* WpkT = (ushort*)d_ws;          // 81920
    ushort* WpT  = WpkT + 81920;           // 65536
    ushort* Ab   = WpT + 65536;            // 3211264
    ushort* Qb   = Ab + 3211264;           // 401408
    ushort* Kb   = Qb + BD * QK_PER_B;     // 401408
    ushort* Vb   = Kb + BD * QK_PER_B;     // 3211264
    ushort* xb   = Vb + BD * V_PER_B;      // 3211264 (x as bf16, [12544][256])
    float*  pb   = (float*)(xb + 3211264); // 320

    prep_all<<<(549184 + 255) / 256, 256, 0, stream>>>(
        x, Wq, Wk, Wv, bq, bk, bv, Wp, xb, WpkT, WpT, pb);

    mfma_qkv<<<dim3(5, NROWS / 128), 256, 0, stream>>>(xb, WpkT, pb, Qb, Kb, Vb);

    natten_attn_m<<<dim3(7, 7, 32), 256, 0, stream>>>(Qb, Kb, Vb, rpb, Ab);

    mfma_out<<<dim3(4, NROWS / 128), 256, 0, stream>>>(Ab, WpT, bp, out);
}